// Round 12
// baseline (128.100 us; speedup 1.0000x reference)
//
#include <hip/hip_runtime.h>
#include <hip/hip_bf16.h>
#include <math.h>

#define D_MODEL 128
#define D_STATE 64
#define LEN 1024
#define BATCH 32
#define KROW 1064        // padded K row stride (f32), [1024..1063] zeroed
#define KC_STRIDE 1056   // shorts per shifted copy

typedef short short8 __attribute__((ext_vector_type(8)));
typedef short short4v __attribute__((ext_vector_type(4)));
typedef float f32x4 __attribute__((ext_vector_type(4)));
typedef float f32x16 __attribute__((ext_vector_type(16)));
typedef float float4u __attribute__((ext_vector_type(4), aligned(4)));  // dword-aligned vec load

// ---------------- helpers ----------------
__device__ __forceinline__ float gelu_cheb(float x) {
    float t = (2.0f * x - 10.0f) * 0.05f;   // (2x - (hi+lo)) / (hi-lo), lo=-5 hi=15
    float r = 6.04831644882f + 8.094460228971f * t;
    float tm1 = 1.0f, tc = t;
    float t2 = 2.0f * t * tc - tm1; r += 1.371512430522f  * t2;
    float t3 = 2.0f * t * t2 - tc;  r += -0.740775295685f * t3;
    float t4 = 2.0f * t * t3 - t2;  r += 0.134773988002f  * t4;
    float t5 = 2.0f * t * t4 - t3;  r += 0.126019270103f  * t5;
    float t6 = 2.0f * t * t5 - t4;  r += -0.239569101196f * t6;
    return r;
}

__device__ __forceinline__ unsigned f2bf(float f) {  // f32 -> bf16 bits, RNE
    unsigned u = __float_as_uint(f);
    return (u + 0x7FFFu + ((u >> 16) & 1u)) >> 16;
}

__device__ __forceinline__ float bf2f(short s) {
    return __uint_as_float(((unsigned)(unsigned short)s) << 16);
}

// ---------------- Kernel 1: params + K via LDS-transpose recurrence ----------------
// Block (d, oct). Side jobs: (a) u[b][d][oct*128..+127] -> bf16 interleaved
// u_bfT[d][jc][b][8] via 8 KB LDS transpose; (b) W1 -> bf16; (c) zero K pad;
// (d) zero acc[32]+counter for glu3's fused finish.
__global__ __launch_bounds__(256) void k_genK4(const float* __restrict__ log_dt,
                                               const float* __restrict__ log_A_real,
                                               const float* __restrict__ A_imag,
                                               const float* __restrict__ B_re,
                                               const float* __restrict__ B_im,
                                               const float* __restrict__ C_re,
                                               const float* __restrict__ C_im,
                                               const float* __restrict__ W1,
                                               const float* __restrict__ u,
                                               short* __restrict__ w1bf,
                                               short* __restrict__ u_bfT,
                                               float* __restrict__ K,
                                               float* __restrict__ accw) {
    __shared__ float Ls[128][68];                 // 34.8 KB
    __shared__ __align__(16) short Ut[4096];      // 8 KB transpose buffer
    int bid = blockIdx.x;             // 1024 = 128 d * 8 oct
    int d = bid >> 3, oct = bid & 7;
    int t = threadIdx.x;

    if (t < 32) { int i = bid * 32 + t; w1bf[i] = (short)f2bf(W1[i]); }
    if (bid == 1 && t < 34) ((unsigned*)accw)[t] = 0u;   // acc[32] + counter + pad

    // ---- u slab convert + LDS transpose: r = batch, c8 = 16-j chunk ----
    {
        int r = t >> 3, c8 = t & 7;
        const float* up = u + ((size_t)(r * D_MODEL + d) << 10) + oct * 128 + c8 * 16;
        float4 a  = *(const float4*)(up);
        float4 b4 = *(const float4*)(up + 4);
        float4 c4 = *(const float4*)(up + 8);
        float4 d4 = *(const float4*)(up + 12);
        uint4 o0, o1;
        o0.x = f2bf(a.x)  | (f2bf(a.y)  << 16);
        o0.y = f2bf(a.z)  | (f2bf(a.w)  << 16);
        o0.z = f2bf(b4.x) | (f2bf(b4.y) << 16);
        o0.w = f2bf(b4.z) | (f2bf(b4.w) << 16);
        o1.x = f2bf(c4.x) | (f2bf(c4.y) << 16);
        o1.y = f2bf(c4.z) | (f2bf(c4.w) << 16);
        o1.z = f2bf(d4.x) | (f2bf(d4.y) << 16);
        o1.w = f2bf(d4.z) | (f2bf(d4.w) << 16);
        int jcl = 2 * c8;
        *(uint4*)&Ut[(jcl * 32 + r) * 8]       = o0;   // j = c8*16 .. +7
        *(uint4*)&Ut[((jcl + 1) * 32 + r) * 8] = o1;   // j = c8*16+8 .. +15
    }

    int w = t >> 6, lane = t & 63;
    int idx = d * D_STATE + lane;
    float dt  = expf(log_dt[d]);
    float Are = -expf(log_A_real[idx]);
    float Aim = A_imag[idx];
    float dre = Are * dt, dim = Aim * dt;
    float e = expf(dre);
    float sn, cs; sincosf(dim, &sn, &cs);
    float zre = e * cs, zim = e * sn;                 // z = A_bar
    float numr = zre - 1.0f, numi = zim;
    float inv = 1.0f / (Are * Are + Aim * Aim);
    float qr = (numr * Are + numi * Aim) * inv;
    float qi = (numi * Are - numr * Aim) * inv;
    float Br = B_re[idx], Bi = B_im[idx];
    float Bbr = qr * Br - qi * Bi;
    float Bbi = qr * Bi + qi * Br;
    float Cr = C_re[idx], Ci = C_im[idx];
    float ar = Cr * Bbr - Ci * Bbi;
    float ai = Cr * Bbi + Ci * Bbr;

    int L0 = oct * 128 + w * 32;
    float fl0 = (float)L0;
    float pre = 0.f, pim = 0.f;
    if (dre * fl0 > -30.f) {                          // dead states contribute < 1e-13
        float e0 = expf(dre * fl0);
        float s0, c0; sincosf(dim * fl0, &s0, &c0);
        pre = e0 * (ar * c0 - ai * s0);
        pim = e0 * (ar * s0 + ai * c0);
    }

    int row0 = w * 32;
#pragma unroll
    for (int r = 0; r < 32; ++r) {
        Ls[row0 + r][lane] = pre;
        float nre = pre * zre - pim * zim;
        pim = pre * zim + pim * zre;
        pre = nre;
    }
    __syncthreads();

    // coalesced contiguous 8 KB store of the transposed slab
    {
        uint4* dst = (uint4*)(u_bfT + (size_t)d * 32768 + oct * 4096) + t * 2;
        const uint4* srcl = (const uint4*)Ut + t * 2;
        dst[0] = srcl[0]; dst[1] = srcl[1];
    }

    if (t < 128) {
        f32x4 s4 = (f32x4){0.f, 0.f, 0.f, 0.f};
#pragma unroll
        for (int c = 0; c < 16; ++c) s4 += *(const f32x4*)&Ls[t][4 * c];
        K[(size_t)d * KROW + oct * 128 + t] = s4.x + s4.y + s4.z + s4.w;
    } else if (oct == 7 && t < 168) {
        K[(size_t)d * KROW + 1024 + (t - 128)] = 0.f;  // zero pad
    }
}

// ---------------- Kernel 2: Toeplitz conv, LDS operands, reg-prefetch dbuf ----------------
// Same MFMA structure as conv9; window-B global loads issued BEFORE phase-A
// compute (no deps) so their latency hides under the MFMAs; stage-B is then
// just 8 ds_write_b128 + barrier. Epilogue: coalesced pg2[b][d][l] 8B stores.
__global__ __launch_bounds__(256) void k_conv10(const float* __restrict__ K,
                                                const short* __restrict__ u_bfT,
                                                const float* __restrict__ Dp,
                                                short* __restrict__ pg2) {
    __shared__ __align__(16) short Kc[8 * KC_STRIDE];   // 16.9 KB
    __shared__ __align__(16) short Us[64 * 256];        // 32 KB window (512 j)
    int bid = blockIdx.x;              // 512 = 128 d * 2 e * 2 ph2
    int d   = bid >> 2;
    int e   = (bid >> 1) & 1;
    int ph2 = bid & 1;
    int t = threadIdx.x;

    // ---- stage Kc: 8 shifted bf16 copies from padded f32 K row ----
    {
        const float* kp = K + (size_t)d * KROW;
        int c = t >> 5;
        short* outp = Kc + c * KC_STRIDE;
        for (int i = (t & 31); i < 132; i += 32) {
            float4u a = *(const float4u*)(kp + 8 * i + c);
            float4u b = *(const float4u*)(kp + 8 * i + c + 4);
            uint4 o;
            o.x = f2bf(a.x) | (f2bf(a.y) << 16);
            o.y = f2bf(a.z) | (f2bf(a.w) << 16);
            o.z = f2bf(b.x) | (f2bf(b.y) << 16);
            o.w = f2bf(b.z) | (f2bf(b.w) << 16);
            *(uint4*)(outp + 8 * i) = o;
        }
    }
    // ---- stage Us window A: j in [0,512) ----
    const uint4* usrc = (const uint4*)(u_bfT + ((size_t)d << 15));
    {
        uint4* dstl = (uint4*)Us;
#pragma unroll
        for (int i = 0; i < 8; ++i) dstl[t + 256 * i] = usrc[t + 256 * i];
    }
    // ---- prefetch window B (j in [512,1024)) into registers ----
    uint4 pf[8];
#pragma unroll
    for (int i = 0; i < 8; ++i) pf[i] = usrc[2048 + t + 256 * i];
    __syncthreads();

    int w = __builtin_amdgcn_readfirstlane(t >> 6);
    int lane = t & 63;
    int mm = lane & 31, h = lane >> 5;
    int cc = (7 - mm) & 7;
    const short* Krow = Kc + cc * KC_STRIDE;
    const short* bbase = Us + mm * 8 + h * 256;     // + ks*512 per step

    int P = 30 + 2 * e;
    int p = e + 2 * (4 * ph2 + w);    // wave-uniform tile pair (p, q)
    int q = P - p;
    int xb = 1023 + 8 * h - mm - cc;
    int xp = xb - 32 * p;
    int xq = xb - 32 * q;

    f32x16 accs[2];
#pragma unroll
    for (int i = 0; i < 16; ++i) { accs[0][i] = 0.f; accs[1][i] = 0.f; }

    int tp = 2 * p + 2;               // tile p trips (<= 32, all in phase A)
    for (int ks = 0; ks < 32; ++ks) {
        short8 bfrag = *(const short8*)(bbase + ks * 512);
        short8 a1 = *(const short8*)&Krow[xq + 16 * ks];
        accs[1] = __builtin_amdgcn_mfma_f32_32x32x16_bf16(a1, bfrag, accs[1], 0, 0, 0);
        if (ks < tp) {
            short8 a2 = *(const short8*)&Krow[xp + 16 * ks];
            accs[0] = __builtin_amdgcn_mfma_f32_32x32x16_bf16(a2, bfrag, accs[0], 0, 0, 0);
        }
    }
    __syncthreads();
    // ---- stage Us window B from registers ----
    {
        uint4* dstl = (uint4*)Us;
#pragma unroll
        for (int i = 0; i < 8; ++i) dstl[t + 256 * i] = pf[i];
    }
    __syncthreads();
    int tq = 2 * q - 30;              // remaining trips for tile q
    for (int ks2 = 0; ks2 < tq; ++ks2) {
        short8 bfrag = *(const short8*)(bbase + ks2 * 512);
        short8 a1 = *(const short8*)&Krow[xq + 16 * (32 + ks2)];
        accs[1] = __builtin_amdgcn_mfma_f32_32x32x16_bf16(a1, bfrag, accs[1], 0, 0, 0);
    }

    // ---- epilogue: skip + GELU + pg2[b][d][l], 8B vector stores ----
    float Dd = Dp[d];
#pragma unroll
    for (int c2 = 0; c2 < 2; ++c2) {
        int I = c2 ? q : p;
        size_t rowb = ((size_t)(mm * D_MODEL + d) << 10) + 32 * I;
#pragma unroll
        for (int rg = 0; rg < 4; ++rg) {
            const short* sp = u_bfT + ((size_t)d << 15) + (4 * I + rg) * 256 + mm * 8 + 4 * h;
            short4v us = *(const short4v*)sp;
            short4v pk;
#pragma unroll
            for (int rr = 0; rr < 4; ++rr) {
                float v = gelu_cheb(accs[c2][rg * 4 + rr] + bf2f(us[rr]) * Dd);
                pk[rr] = (short)f2bf(v);
            }
            *(short4v*)(pg2 + rowb + 8 * rg + 4 * h) = pk;
        }
    }
}

// ---------------- Kernel 3: MFMA GEMM + GLU + pooling + fused finish ----------------
// x staged from pg2[b][d][l] into xs[l][k] bf16 (stride 136); B-frags from LDS.
// Block partial -> device atomicAdd(acc[b]); last of 512 blocks writes out.
__global__ __launch_bounds__(256) void k_glu3(const short* __restrict__ pg2,
                                              const short* __restrict__ w1bf,
                                              const float* __restrict__ b1,
                                              const float* __restrict__ Wdec,
                                              const float* __restrict__ bdec,
                                              float* __restrict__ accw,
                                              float* __restrict__ out) {
    __shared__ __align__(16) short xs[64 * 136];   // 17.4 KB
    __shared__ float red[4];
    __shared__ int isLast;
    int b = blockIdx.y;
    int lc = blockIdx.x;
    int l0 = lc * 64;
    int t = threadIdx.x;

    // ---- stage: thread = (d-pair dp, l-quarter lq); ds_write_b32 pairs ----
    {
        int dp = t & 63, lq = t >> 6;
        const short* r0 = pg2 + (((size_t)b * D_MODEL + 2 * dp) << 10) + l0 + lq * 16;
        short8 a0 = *(const short8*)r0;            // k=2dp,   l = lq*16+0..7
        short8 a1 = *(const short8*)(r0 + 8);      //          l = lq*16+8..15
        short8 c0 = *(const short8*)(r0 + 1024);   // k=2dp+1
        short8 c1 = *(const short8*)(r0 + 1032);
#pragma unroll
        for (int i = 0; i < 8; ++i) {
            *(unsigned*)&xs[(lq * 16 + i) * 136 + 2 * dp] =
                (unsigned)(unsigned short)a0[i] | ((unsigned)(unsigned short)c0[i] << 16);
            *(unsigned*)&xs[(lq * 16 + 8 + i) * 136 + 2 * dp] =
                (unsigned)(unsigned short)a1[i] | ((unsigned)(unsigned short)c1[i] << 16);
        }
    }

    int wv = t >> 6, lane = t & 63;
    int m = lane & 15, q = lane >> 4;

    const short* wA0 = w1bf + ((2 * wv + 0) * 16 + m) * D_MODEL;
    const short* wA1 = w1bf + ((2 * wv + 1) * 16 + m) * D_MODEL;

    short8 aA0[4], aA1[4], aB0[4], aB1[4];
#pragma unroll
    for (int kki = 0; kki < 4; ++kki) {
        int ko = kki * 32 + q * 8;
        aA0[kki] = *(const short8*)(wA0 + ko);
        aA1[kki] = *(const short8*)(wA1 + ko);
        aB0[kki] = *(const short8*)(wA0 + 128 * D_MODEL + ko);
        aB1[kki] = *(const short8*)(wA1 + 128 * D_MODEL + ko);
    }
    __syncthreads();

    f32x4 accA[2][4], accB[2][4];
#pragma unroll
    for (int p = 0; p < 2; ++p)
#pragma unroll
        for (int nt = 0; nt < 4; ++nt) {
            accA[p][nt] = (f32x4){0.f, 0.f, 0.f, 0.f};
            accB[p][nt] = (f32x4){0.f, 0.f, 0.f, 0.f};
        }

#pragma unroll
    for (int kki = 0; kki < 4; ++kki) {
        int ko = kki * 32 + q * 8;
        short8 bfr[4];
#pragma unroll
        for (int nt = 0; nt < 4; ++nt)
            bfr[nt] = *(const short8*)&xs[(nt * 16 + m) * 136 + ko];
#pragma unroll
        for (int nt = 0; nt < 4; ++nt) {
            accA[0][nt] = __builtin_amdgcn_mfma_f32_16x16x32_bf16(aA0[kki], bfr[nt], accA[0][nt], 0, 0, 0);
            accA[1][nt] = __builtin_amdgcn_mfma_f32_16x16x32_bf16(aA1[kki], bfr[nt], accA[1][nt], 0, 0, 0);
            accB[0][nt] = __builtin_amdgcn_mfma_f32_16x16x32_bf16(aB0[kki], bfr[nt], accB[0][nt], 0, 0, 0);
            accB[1][nt] = __builtin_amdgcn_mfma_f32_16x16x32_bf16(aB1[kki], bfr[nt], accB[1][nt], 0, 0, 0);
        }
    }

    float s = 0.f;
#pragma unroll
    for (int p = 0; p < 2; ++p) {
        int oA = (2 * wv + p) * 16 + q * 4;
#pragma unroll
        for (int r = 0; r < 4; ++r) {
            int o = oA + r;
            float wd  = Wdec[o];
            float ba  = b1[o];
            float bb1 = b1[o + 128];
#pragma unroll
            for (int nt = 0; nt < 4; ++nt) {
                float aa  = accA[p][nt][r] + ba;
                float bbv = accB[p][nt][r] + bb1;
                float g = fminf(fmaxf(0.25f * bbv + 0.5f, 0.f), 1.f);
                s += wd * aa * g;
            }
        }
    }
#pragma unroll
    for (int off = 32; off > 0; off >>= 1) s += __shfl_down(s, off, 64);
    if (lane == 0) red[wv] = s;
    __syncthreads();
    if (t == 0) {
        float bs = red[0] + red[1] + red[2] + red[3];
        atomicAdd(&accw[b], bs);
        __threadfence();
        unsigned old = atomicAdd((unsigned*)(accw + 32), 1u);
        isLast = (old == 511u);
    }
    __syncthreads();
    if (isLast && t < BATCH) {
        float v = atomicAdd(&accw[t], 0.0f);     // coherent read
        out[t] = v * (1.0f / (float)LEN) + bdec[0];
    }
}

extern "C" void kernel_launch(void* const* d_in, const int* in_sizes, int n_in,
                              void* d_out, int out_size, void* d_ws, size_t ws_size,
                              hipStream_t stream) {
    const float* u          = (const float*)d_in[0];
    const float* log_dt     = (const float*)d_in[1];
    const float* log_A_real = (const float*)d_in[2];
    const float* A_imag     = (const float*)d_in[3];
    const float* B_re       = (const float*)d_in[4];
    const float* B_im       = (const float*)d_in[5];
    const float* C_re       = (const float*)d_in[6];
    const float* C_im       = (const float*)d_in[7];
    const float* Dp         = (const float*)d_in[8];
    const float* W1         = (const float*)d_in[9];
    const float* b1         = (const float*)d_in[10];
    const float* Wdec       = (const float*)d_in[11];
    const float* bdec       = (const float*)d_in[12];
    float* out = (float*)d_out;

    float* w = (float*)d_ws;
    float* K      = w;                                    // 128*1064 f32 (padded)
    float* accw   = K + (size_t)D_MODEL * KROW;           // 32 acc + counter + pad (64)
    short* u_bfT  = (short*)(accw + 64);                  // [d][j>>3][b][j&7] bf16
    short* pg2    = u_bfT + (size_t)BATCH * D_MODEL * LEN; // [b][d][l] bf16
    short* w1bf   = pg2 + (size_t)BATCH * LEN * D_MODEL;  // 256*128 bf16

    k_genK4<<<D_MODEL * 8, 256, 0, stream>>>(log_dt, log_A_real, A_imag, B_re, B_im,
                                             C_re, C_im, W1, u, w1bf, u_bfT, K, accw);
    k_conv10<<<512, 256, 0, stream>>>(K, u_bfT, Dp, pg2);
    k_glu3<<<dim3(16, BATCH), 256, 0, stream>>>(pg2, w1bf, b1, Wdec, bdec, accw, out);
}

// Round 13
// 123.947 us; speedup vs baseline: 1.0335x; 1.0335x over previous
//
#include <hip/hip_runtime.h>
#include <hip/hip_bf16.h>
#include <math.h>

#define D_MODEL 128
#define D_STATE 64
#define LEN 1024
#define BATCH 32
#define KROW 1064        // padded K row stride (f32), [1024..1063] zeroed
#define KC_STRIDE 1056   // shorts per shifted copy

typedef short short8 __attribute__((ext_vector_type(8)));
typedef short short4v __attribute__((ext_vector_type(4)));
typedef float f32x4 __attribute__((ext_vector_type(4)));
typedef float f32x16 __attribute__((ext_vector_type(16)));
typedef float float4u __attribute__((ext_vector_type(4), aligned(4)));  // dword-aligned vec load

// ---------------- helpers ----------------
__device__ __forceinline__ float gelu_cheb(float x) {
    float t = (2.0f * x - 10.0f) * 0.05f;   // (2x - (hi+lo)) / (hi-lo), lo=-5 hi=15
    float r = 6.04831644882f + 8.094460228971f * t;
    float tm1 = 1.0f, tc = t;
    float t2 = 2.0f * t * tc - tm1; r += 1.371512430522f  * t2;
    float t3 = 2.0f * t * t2 - tc;  r += -0.740775295685f * t3;
    float t4 = 2.0f * t * t3 - t2;  r += 0.134773988002f  * t4;
    float t5 = 2.0f * t * t4 - t3;  r += 0.126019270103f  * t5;
    float t6 = 2.0f * t * t5 - t4;  r += -0.239569101196f * t6;
    return r;
}

__device__ __forceinline__ unsigned f2bf(float f) {  // f32 -> bf16 bits, RNE
    unsigned u = __float_as_uint(f);
    return (u + 0x7FFFu + ((u >> 16) & 1u)) >> 16;
}

__device__ __forceinline__ float bf2f(short s) {
    return __uint_as_float(((unsigned)(unsigned short)s) << 16);
}

// ---------------- Kernel 1: params + K via LDS-transpose recurrence ----------------
// Block (d, oct). Side jobs: (a) u[b][d][oct*128..+127] -> bf16 interleaved
// u_bfT[d][jc][b][8] via 8 KB LDS transpose; (b) W1 -> bf16; (c) zero K pad;
// (d) zero acc[32]+counter for glu3's fused finish.
__global__ __launch_bounds__(256) void k_genK4(const float* __restrict__ log_dt,
                                               const float* __restrict__ log_A_real,
                                               const float* __restrict__ A_imag,
                                               const float* __restrict__ B_re,
                                               const float* __restrict__ B_im,
                                               const float* __restrict__ C_re,
                                               const float* __restrict__ C_im,
                                               const float* __restrict__ W1,
                                               const float* __restrict__ u,
                                               short* __restrict__ w1bf,
                                               short* __restrict__ u_bfT,
                                               float* __restrict__ K,
                                               float* __restrict__ accw) {
    __shared__ float Ls[128][68];                 // 34.8 KB
    __shared__ __align__(16) short Ut[4096];      // 8 KB transpose buffer
    int bid = blockIdx.x;             // 1024 = 128 d * 8 oct
    int d = bid >> 3, oct = bid & 7;
    int t = threadIdx.x;

    if (t < 32) { int i = bid * 32 + t; w1bf[i] = (short)f2bf(W1[i]); }
    if (bid == 1 && t < 34) ((unsigned*)accw)[t] = 0u;   // acc[32] + counter

    // ---- u slab convert + LDS transpose: r = batch, c8 = 16-j chunk ----
    {
        int r = t >> 3, c8 = t & 7;
        const float* up = u + ((size_t)(r * D_MODEL + d) << 10) + oct * 128 + c8 * 16;
        float4 a  = *(const float4*)(up);
        float4 b4 = *(const float4*)(up + 4);
        float4 c4 = *(const float4*)(up + 8);
        float4 d4 = *(const float4*)(up + 12);
        uint4 o0, o1;
        o0.x = f2bf(a.x)  | (f2bf(a.y)  << 16);
        o0.y = f2bf(a.z)  | (f2bf(a.w)  << 16);
        o0.z = f2bf(b4.x) | (f2bf(b4.y) << 16);
        o0.w = f2bf(b4.z) | (f2bf(b4.w) << 16);
        o1.x = f2bf(c4.x) | (f2bf(c4.y) << 16);
        o1.y = f2bf(c4.z) | (f2bf(c4.w) << 16);
        o1.z = f2bf(d4.x) | (f2bf(d4.y) << 16);
        o1.w = f2bf(d4.z) | (f2bf(d4.w) << 16);
        int jcl = 2 * c8;
        *(uint4*)&Ut[(jcl * 32 + r) * 8]       = o0;   // j = c8*16 .. +7
        *(uint4*)&Ut[((jcl + 1) * 32 + r) * 8] = o1;   // j = c8*16+8 .. +15
    }

    int w = t >> 6, lane = t & 63;
    int idx = d * D_STATE + lane;
    float dt  = expf(log_dt[d]);
    float Are = -expf(log_A_real[idx]);
    float Aim = A_imag[idx];
    float dre = Are * dt, dim = Aim * dt;
    float e = expf(dre);
    float sn, cs; sincosf(dim, &sn, &cs);
    float zre = e * cs, zim = e * sn;                 // z = A_bar
    float numr = zre - 1.0f, numi = zim;
    float inv = 1.0f / (Are * Are + Aim * Aim);
    float qr = (numr * Are + numi * Aim) * inv;
    float qi = (numi * Are - numr * Aim) * inv;
    float Br = B_re[idx], Bi = B_im[idx];
    float Bbr = qr * Br - qi * Bi;
    float Bbi = qr * Bi + qi * Br;
    float Cr = C_re[idx], Ci = C_im[idx];
    float ar = Cr * Bbr - Ci * Bbi;
    float ai = Cr * Bbi + Ci * Bbr;

    int L0 = oct * 128 + w * 32;
    float fl0 = (float)L0;
    float pre = 0.f, pim = 0.f;
    if (dre * fl0 > -30.f) {                          // dead states contribute < 1e-13
        float e0 = expf(dre * fl0);
        float s0, c0; sincosf(dim * fl0, &s0, &c0);
        pre = e0 * (ar * c0 - ai * s0);
        pim = e0 * (ar * s0 + ai * c0);
    }

    int row0 = w * 32;
#pragma unroll
    for (int r = 0; r < 32; ++r) {
        Ls[row0 + r][lane] = pre;
        float nre = pre * zre - pim * zim;
        pim = pre * zim + pim * zre;
        pre = nre;
    }
    __syncthreads();

    // coalesced contiguous 8 KB store of the transposed slab
    {
        uint4* dst = (uint4*)(u_bfT + (size_t)d * 32768 + oct * 4096) + t * 2;
        const uint4* srcl = (const uint4*)Ut + t * 2;
        dst[0] = srcl[0]; dst[1] = srcl[1];
    }

    if (t < 128) {
        f32x4 s4 = (f32x4){0.f, 0.f, 0.f, 0.f};
#pragma unroll
        for (int c = 0; c < 16; ++c) s4 += *(const f32x4*)&Ls[t][4 * c];
        K[(size_t)d * KROW + oct * 128 + t] = s4.x + s4.y + s4.z + s4.w;
    } else if (oct == 7 && t < 168) {
        K[(size_t)d * KROW + 1024 + (t - 128)] = 0.f;  // zero pad
    }
}

// ---------------- Kernel 2: Toeplitz conv (R11's conv9, no reg prefetch) ----------------
// mfma_f32_32x32x16: M = 32 l (tile I), N = 32 batch, K = 16 j. Both operands
// from LDS; balanced wave pairs (p, P-p). Epilogue: coalesced pg2[b][d][l].
__global__ __launch_bounds__(256) void k_conv9(const float* __restrict__ K,
                                               const short* __restrict__ u_bfT,
                                               const float* __restrict__ Dp,
                                               short* __restrict__ pg2) {
    __shared__ __align__(16) short Kc[8 * KC_STRIDE];   // 16.9 KB
    __shared__ __align__(16) short Us[64 * 256];        // 32 KB window (512 j)
    int bid = blockIdx.x;              // 512 = 128 d * 2 e * 2 ph2
    int d   = bid >> 2;
    int e   = (bid >> 1) & 1;
    int ph2 = bid & 1;
    int t = threadIdx.x;

    // ---- stage Kc: 8 shifted bf16 copies from padded f32 K row ----
    {
        const float* kp = K + (size_t)d * KROW;
        int c = t >> 5;
        short* outp = Kc + c * KC_STRIDE;
        for (int i = (t & 31); i < 132; i += 32) {
            float4u a = *(const float4u*)(kp + 8 * i + c);
            float4u b = *(const float4u*)(kp + 8 * i + c + 4);
            uint4 o;
            o.x = f2bf(a.x) | (f2bf(a.y) << 16);
            o.y = f2bf(a.z) | (f2bf(a.w) << 16);
            o.z = f2bf(b.x) | (f2bf(b.y) << 16);
            o.w = f2bf(b.z) | (f2bf(b.w) << 16);
            *(uint4*)(outp + 8 * i) = o;
        }
    }
    // ---- stage Us window A: j in [0,512) ----
    const uint4* usrc = (const uint4*)(u_bfT + ((size_t)d << 15));
    {
        uint4* dstl = (uint4*)Us;
        for (int v = t; v < 2048; v += 256) dstl[v] = usrc[v];
    }
    __syncthreads();

    int w = __builtin_amdgcn_readfirstlane(t >> 6);
    int lane = t & 63;
    int mm = lane & 31, h = lane >> 5;
    int cc = (7 - mm) & 7;
    const short* Krow = Kc + cc * KC_STRIDE;
    const short* bbase = Us + mm * 8 + h * 256;     // + ks*512 per step

    int P = 30 + 2 * e;
    int p = e + 2 * (4 * ph2 + w);    // wave-uniform tile pair (p, q)
    int q = P - p;
    int xb = 1023 + 8 * h - mm - cc;
    int xp = xb - 32 * p;
    int xq = xb - 32 * q;

    f32x16 accs[2];
#pragma unroll
    for (int i = 0; i < 16; ++i) { accs[0][i] = 0.f; accs[1][i] = 0.f; }

    int tp = 2 * p + 2;               // tile p trips (<= 32, all in phase A)
    for (int ks = 0; ks < 32; ++ks) {
        short8 bfrag = *(const short8*)(bbase + ks * 512);
        short8 a1 = *(const short8*)&Krow[xq + 16 * ks];
        accs[1] = __builtin_amdgcn_mfma_f32_32x32x16_bf16(a1, bfrag, accs[1], 0, 0, 0);
        if (ks < tp) {
            short8 a2 = *(const short8*)&Krow[xp + 16 * ks];
            accs[0] = __builtin_amdgcn_mfma_f32_32x32x16_bf16(a2, bfrag, accs[0], 0, 0, 0);
        }
    }
    __syncthreads();
    // ---- stage Us window B: j in [512,1024) ----
    {
        uint4* dstl = (uint4*)Us;
        for (int v = t; v < 2048; v += 256) dstl[v] = usrc[v + 2048];
    }
    __syncthreads();
    int tq = 2 * q - 30;              // remaining trips for tile q
    for (int ks2 = 0; ks2 < tq; ++ks2) {
        short8 bfrag = *(const short8*)(bbase + ks2 * 512);
        short8 a1 = *(const short8*)&Krow[xq + 16 * (32 + ks2)];
        accs[1] = __builtin_amdgcn_mfma_f32_32x32x16_bf16(a1, bfrag, accs[1], 0, 0, 0);
    }

    // ---- epilogue: skip + GELU + pg2[b][d][l], 8B vector stores ----
    // C col = mm = batch, row = (reg&3) + 8*(reg>>2) + 4*h = rr + 8*rg + 4*h
    float Dd = Dp[d];
#pragma unroll
    for (int c2 = 0; c2 < 2; ++c2) {
        int I = c2 ? q : p;
        size_t rowb = ((size_t)(mm * D_MODEL + d) << 10) + 32 * I;
#pragma unroll
        for (int rg = 0; rg < 4; ++rg) {
            const short* sp = u_bfT + ((size_t)d << 15) + (4 * I + rg) * 256 + mm * 8 + 4 * h;
            short4v us = *(const short4v*)sp;
            short4v pk;
#pragma unroll
            for (int rr = 0; rr < 4; ++rr) {
                float v = gelu_cheb(accs[c2][rg * 4 + rr] + bf2f(us[rr]) * Dd);
                pk[rr] = (short)f2bf(v);
            }
            *(short4v*)(pg2 + rowb + 8 * rg + 4 * h) = pk;
        }
    }
}

// ---------------- Kernel 3: MFMA GEMM + GLU + pooling + fused finish ----------------
// x staged from pg2[b][d][l] into xs[l][k] bf16 (stride 136); B-frags from LDS.
// Block partial -> device atomicAdd(acc[b]); last of 512 blocks writes out.
__global__ __launch_bounds__(256) void k_glu3(const short* __restrict__ pg2,
                                              const short* __restrict__ w1bf,
                                              const float* __restrict__ b1,
                                              const float* __restrict__ Wdec,
                                              const float* __restrict__ bdec,
                                              float* __restrict__ accw,
                                              float* __restrict__ out) {
    __shared__ __align__(16) short xs[64 * 136];   // 17.4 KB
    __shared__ float red[4];
    __shared__ int isLast;
    int b = blockIdx.y;
    int lc = blockIdx.x;
    int l0 = lc * 64;
    int t = threadIdx.x;

    // ---- stage: thread = (d-pair dp, l-quarter lq); ds_write_b32 pairs ----
    {
        int dp = t & 63, lq = t >> 6;
        const short* r0 = pg2 + (((size_t)b * D_MODEL + 2 * dp) << 10) + l0 + lq * 16;
        short8 a0 = *(const short8*)r0;            // k=2dp,   l = lq*16+0..7
        short8 a1 = *(const short8*)(r0 + 8);      //          l = lq*16+8..15
        short8 c0 = *(const short8*)(r0 + 1024);   // k=2dp+1
        short8 c1 = *(const short8*)(r0 + 1032);
#pragma unroll
        for (int i = 0; i < 8; ++i) {
            *(unsigned*)&xs[(lq * 16 + i) * 136 + 2 * dp] =
                (unsigned)(unsigned short)a0[i] | ((unsigned)(unsigned short)c0[i] << 16);
            *(unsigned*)&xs[(lq * 16 + 8 + i) * 136 + 2 * dp] =
                (unsigned)(unsigned short)a1[i] | ((unsigned)(unsigned short)c1[i] << 16);
        }
    }

    int wv = t >> 6, lane = t & 63;
    int m = lane & 15, q = lane >> 4;

    const short* wA0 = w1bf + ((2 * wv + 0) * 16 + m) * D_MODEL;
    const short* wA1 = w1bf + ((2 * wv + 1) * 16 + m) * D_MODEL;

    short8 aA0[4], aA1[4], aB0[4], aB1[4];
#pragma unroll
    for (int kki = 0; kki < 4; ++kki) {
        int ko = kki * 32 + q * 8;
        aA0[kki] = *(const short8*)(wA0 + ko);
        aA1[kki] = *(const short8*)(wA1 + ko);
        aB0[kki] = *(const short8*)(wA0 + 128 * D_MODEL + ko);
        aB1[kki] = *(const short8*)(wA1 + 128 * D_MODEL + ko);
    }
    __syncthreads();

    f32x4 accA[2][4], accB[2][4];
#pragma unroll
    for (int p = 0; p < 2; ++p)
#pragma unroll
        for (int nt = 0; nt < 4; ++nt) {
            accA[p][nt] = (f32x4){0.f, 0.f, 0.f, 0.f};
            accB[p][nt] = (f32x4){0.f, 0.f, 0.f, 0.f};
        }

#pragma unroll
    for (int kki = 0; kki < 4; ++kki) {
        int ko = kki * 32 + q * 8;
        short8 bfr[4];
#pragma unroll
        for (int nt = 0; nt < 4; ++nt)
            bfr[nt] = *(const short8*)&xs[(nt * 16 + m) * 136 + ko];
#pragma unroll
        for (int nt = 0; nt < 4; ++nt) {
            accA[0][nt] = __builtin_amdgcn_mfma_f32_16x16x32_bf16(aA0[kki], bfr[nt], accA[0][nt], 0, 0, 0);
            accA[1][nt] = __builtin_amdgcn_mfma_f32_16x16x32_bf16(aA1[kki], bfr[nt], accA[1][nt], 0, 0, 0);
            accB[0][nt] = __builtin_amdgcn_mfma_f32_16x16x32_bf16(aB0[kki], bfr[nt], accB[0][nt], 0, 0, 0);
            accB[1][nt] = __builtin_amdgcn_mfma_f32_16x16x32_bf16(aB1[kki], bfr[nt], accB[1][nt], 0, 0, 0);
        }
    }

    float s = 0.f;
#pragma unroll
    for (int p = 0; p < 2; ++p) {
        int oA = (2 * wv + p) * 16 + q * 4;
#pragma unroll
        for (int r = 0; r < 4; ++r) {
            int o = oA + r;
            float wd  = Wdec[o];
            float ba  = b1[o];
            float bb1 = b1[o + 128];
#pragma unroll
            for (int nt = 0; nt < 4; ++nt) {
                float aa  = accA[p][nt][r] + ba;
                float bbv = accB[p][nt][r] + bb1;
                float g = fminf(fmaxf(0.25f * bbv + 0.5f, 0.f), 1.f);
                s += wd * aa * g;
            }
        }
    }
#pragma unroll
    for (int off = 32; off > 0; off >>= 1) s += __shfl_down(s, off, 64);
    if (lane == 0) red[wv] = s;
    __syncthreads();
    if (t == 0) {
        float bs = red[0] + red[1] + red[2] + red[3];
        atomicAdd(&accw[b], bs);
        __threadfence();
        unsigned old = atomicAdd((unsigned*)(accw + 32), 1u);
        isLast = (old == 511u);
    }
    __syncthreads();
    if (isLast && t < BATCH) {
        float v = atomicAdd(&accw[t], 0.0f);     // coherent read
        out[t] = v * (1.0f / (float)LEN) + bdec[0];
    }
}

extern "C" void kernel_launch(void* const* d_in, const int* in_sizes, int n_in,
                              void* d_out, int out_size, void* d_ws, size_t ws_size,
                              hipStream_t stream) {
    const float* u          = (const float*)d_in[0];
    const float* log_dt     = (const float*)d_in[1];
    const float* log_A_real = (const float*)d_in[2];
    const float* A_imag     = (const float*)d_in[3];
    const float* B_re       = (const float*)d_in[4];
    const float* B_im       = (const float*)d_in[5];
    const float* C_re       = (const float*)d_in[6];
    const float* C_im       = (const float*)d_in[7];
    const float* Dp         = (const float*)d_in[8];
    const float* W1         = (const float*)d_in[9];
    const float* b1         = (const float*)d_in[10];
    const float* Wdec       = (const float*)d_in[11];
    const float* bdec       = (const float*)d_in[12];
    float* out = (float*)d_out;

    float* w = (float*)d_ws;
    float* K      = w;                                    // 128*1064 f32 (padded)
    float* accw   = K + (size_t)D_MODEL * KROW;           // 32 acc + counter + pad (64)
    short* u_bfT  = (short*)(accw + 64);                  // [d][j>>3][b][j&7] bf16
    short* pg2    = u_bfT + (size_t)BATCH * D_MODEL * LEN; // [b][d][l] bf16
    short* w1bf   = pg2 + (size_t)BATCH * LEN * D_MODEL;  // 256*128 bf16

    k_genK4<<<D_MODEL * 8, 256, 0, stream>>>(log_dt, log_A_real, A_imag, B_re, B_im,
                                             C_re, C_im, W1, u, w1bf, u_bfT, K, accw);
    k_conv9<<<512, 256, 0, stream>>>(K, u_bfT, Dp, pg2);
    k_glu3<<<dim3(16, BATCH), 256, 0, stream>>>(pg2, w1bf, b1, Wdec, bdec, accw, out);
}

// Round 14
// 114.562 us; speedup vs baseline: 1.1182x; 1.0819x over previous
//
#include <hip/hip_runtime.h>
#include <hip/hip_bf16.h>
#include <math.h>

#define D_MODEL 128
#define D_STATE 64
#define LEN 1024
#define BATCH 32
#define KROW 1064        // padded K row stride (f32), [1024..1063] zeroed
#define KC_STRIDE 1056   // shorts per shifted copy

typedef short short8 __attribute__((ext_vector_type(8)));
typedef short short4v __attribute__((ext_vector_type(4)));
typedef float f32x4 __attribute__((ext_vector_type(4)));
typedef float f32x16 __attribute__((ext_vector_type(16)));
typedef float float4u __attribute__((ext_vector_type(4), aligned(4)));  // dword-aligned vec load

// ---------------- helpers ----------------
__device__ __forceinline__ float gelu_cheb(float x) {
    float t = (2.0f * x - 10.0f) * 0.05f;   // (2x - (hi+lo)) / (hi-lo), lo=-5 hi=15
    float r = 6.04831644882f + 8.094460228971f * t;
    float tm1 = 1.0f, tc = t;
    float t2 = 2.0f * t * tc - tm1; r += 1.371512430522f  * t2;
    float t3 = 2.0f * t * t2 - tc;  r += -0.740775295685f * t3;
    float t4 = 2.0f * t * t3 - t2;  r += 0.134773988002f  * t4;
    float t5 = 2.0f * t * t4 - t3;  r += 0.126019270103f  * t5;
    float t6 = 2.0f * t * t5 - t4;  r += -0.239569101196f * t6;
    return r;
}

__device__ __forceinline__ unsigned f2bf(float f) {  // f32 -> bf16 bits, RNE
    unsigned u = __float_as_uint(f);
    return (u + 0x7FFFu + ((u >> 16) & 1u)) >> 16;
}

__device__ __forceinline__ float bf2f(short s) {
    return __uint_as_float(((unsigned)(unsigned short)s) << 16);
}

// ---------------- Kernel 1: params + K via LDS-transpose recurrence ----------------
// Block (d, oct). Side jobs: (a) u[b][d][oct*128..+127] -> bf16 interleaved
// u_bfT[d][jc][b][8] via 8 KB LDS transpose; (b) W1 -> bf16; (c) zero K pad.
__global__ __launch_bounds__(256) void k_genK4(const float* __restrict__ log_dt,
                                               const float* __restrict__ log_A_real,
                                               const float* __restrict__ A_imag,
                                               const float* __restrict__ B_re,
                                               const float* __restrict__ B_im,
                                               const float* __restrict__ C_re,
                                               const float* __restrict__ C_im,
                                               const float* __restrict__ W1,
                                               const float* __restrict__ u,
                                               short* __restrict__ w1bf,
                                               short* __restrict__ u_bfT,
                                               float* __restrict__ K) {
    __shared__ float Ls[128][68];                 // 34.8 KB
    __shared__ __align__(16) short Ut[4096];      // 8 KB transpose buffer
    int bid = blockIdx.x;             // 1024 = 128 d * 8 oct
    int d = bid >> 3, oct = bid & 7;
    int t = threadIdx.x;

    if (t < 32) { int i = bid * 32 + t; w1bf[i] = (short)f2bf(W1[i]); }

    // ---- u slab convert + LDS transpose: r = batch, c8 = 16-j chunk ----
    {
        int r = t >> 3, c8 = t & 7;
        const float* up = u + ((size_t)(r * D_MODEL + d) << 10) + oct * 128 + c8 * 16;
        float4 a  = *(const float4*)(up);
        float4 b4 = *(const float4*)(up + 4);
        float4 c4 = *(const float4*)(up + 8);
        float4 d4 = *(const float4*)(up + 12);
        uint4 o0, o1;
        o0.x = f2bf(a.x)  | (f2bf(a.y)  << 16);
        o0.y = f2bf(a.z)  | (f2bf(a.w)  << 16);
        o0.z = f2bf(b4.x) | (f2bf(b4.y) << 16);
        o0.w = f2bf(b4.z) | (f2bf(b4.w) << 16);
        o1.x = f2bf(c4.x) | (f2bf(c4.y) << 16);
        o1.y = f2bf(c4.z) | (f2bf(c4.w) << 16);
        o1.z = f2bf(d4.x) | (f2bf(d4.y) << 16);
        o1.w = f2bf(d4.z) | (f2bf(d4.w) << 16);
        int jcl = 2 * c8;
        *(uint4*)&Ut[(jcl * 32 + r) * 8]       = o0;   // j = c8*16 .. +7
        *(uint4*)&Ut[((jcl + 1) * 32 + r) * 8] = o1;   // j = c8*16+8 .. +15
    }

    int w = t >> 6, lane = t & 63;
    int idx = d * D_STATE + lane;
    float dt  = expf(log_dt[d]);
    float Are = -expf(log_A_real[idx]);
    float Aim = A_imag[idx];
    float dre = Are * dt, dim = Aim * dt;
    float e = expf(dre);
    float sn, cs; sincosf(dim, &sn, &cs);
    float zre = e * cs, zim = e * sn;                 // z = A_bar
    float numr = zre - 1.0f, numi = zim;
    float inv = 1.0f / (Are * Are + Aim * Aim);
    float qr = (numr * Are + numi * Aim) * inv;
    float qi = (numi * Are - numr * Aim) * inv;
    float Br = B_re[idx], Bi = B_im[idx];
    float Bbr = qr * Br - qi * Bi;
    float Bbi = qr * Bi + qi * Br;
    float Cr = C_re[idx], Ci = C_im[idx];
    float ar = Cr * Bbr - Ci * Bbi;
    float ai = Cr * Bbi + Ci * Bbr;

    int L0 = oct * 128 + w * 32;
    float fl0 = (float)L0;
    float pre = 0.f, pim = 0.f;
    if (dre * fl0 > -30.f) {                          // dead states contribute < 1e-13
        float e0 = expf(dre * fl0);
        float s0, c0; sincosf(dim * fl0, &s0, &c0);
        pre = e0 * (ar * c0 - ai * s0);
        pim = e0 * (ar * s0 + ai * c0);
    }

    int row0 = w * 32;
#pragma unroll
    for (int r = 0; r < 32; ++r) {
        Ls[row0 + r][lane] = pre;
        float nre = pre * zre - pim * zim;
        pim = pre * zim + pim * zre;
        pre = nre;
    }
    __syncthreads();

    // coalesced contiguous 8 KB store of the transposed slab
    {
        uint4* dst = (uint4*)(u_bfT + (size_t)d * 32768 + oct * 4096) + t * 2;
        const uint4* srcl = (const uint4*)Ut + t * 2;
        dst[0] = srcl[0]; dst[1] = srcl[1];
    }

    if (t < 128) {
        f32x4 s4 = (f32x4){0.f, 0.f, 0.f, 0.f};
#pragma unroll
        for (int c = 0; c < 16; ++c) s4 += *(const f32x4*)&Ls[t][4 * c];
        K[(size_t)d * KROW + oct * 128 + t] = s4.x + s4.y + s4.z + s4.w;
    } else if (oct == 7 && t < 168) {
        K[(size_t)d * KROW + 1024 + (t - 128)] = 0.f;  // zero pad
    }
}

// ---------------- Kernel 2: Toeplitz conv, both operands LDS, balanced pairs ----------------
// mfma_f32_32x32x16: M = 32 l (tile I), N = 32 batch, K = 16 j. Both operands
// from LDS; balanced wave pairs (p, P-p). Epilogue: coalesced pg2[b][d][l].
__global__ __launch_bounds__(256) void k_conv9(const float* __restrict__ K,
                                               const short* __restrict__ u_bfT,
                                               const float* __restrict__ Dp,
                                               short* __restrict__ pg2) {
    __shared__ __align__(16) short Kc[8 * KC_STRIDE];   // 16.9 KB
    __shared__ __align__(16) short Us[64 * 256];        // 32 KB window (512 j)
    int bid = blockIdx.x;              // 512 = 128 d * 2 e * 2 ph2
    int d   = bid >> 2;
    int e   = (bid >> 1) & 1;
    int ph2 = bid & 1;
    int t = threadIdx.x;

    // ---- stage Kc: 8 shifted bf16 copies from padded f32 K row ----
    {
        const float* kp = K + (size_t)d * KROW;
        int c = t >> 5;
        short* outp = Kc + c * KC_STRIDE;
        for (int i = (t & 31); i < 132; i += 32) {
            float4u a = *(const float4u*)(kp + 8 * i + c);
            float4u b = *(const float4u*)(kp + 8 * i + c + 4);
            uint4 o;
            o.x = f2bf(a.x) | (f2bf(a.y) << 16);
            o.y = f2bf(a.z) | (f2bf(a.w) << 16);
            o.z = f2bf(b.x) | (f2bf(b.y) << 16);
            o.w = f2bf(b.z) | (f2bf(b.w) << 16);
            *(uint4*)(outp + 8 * i) = o;
        }
    }
    // ---- stage Us window A: j in [0,512) ----
    const uint4* usrc = (const uint4*)(u_bfT + ((size_t)d << 15));
    {
        uint4* dstl = (uint4*)Us;
        for (int v = t; v < 2048; v += 256) dstl[v] = usrc[v];
    }
    __syncthreads();

    int w = __builtin_amdgcn_readfirstlane(t >> 6);
    int lane = t & 63;
    int mm = lane & 31, h = lane >> 5;
    int cc = (7 - mm) & 7;
    const short* Krow = Kc + cc * KC_STRIDE;
    const short* bbase = Us + mm * 8 + h * 256;     // + ks*512 per step

    int P = 30 + 2 * e;
    int p = e + 2 * (4 * ph2 + w);    // wave-uniform tile pair (p, q)
    int q = P - p;
    int xb = 1023 + 8 * h - mm - cc;
    int xp = xb - 32 * p;
    int xq = xb - 32 * q;

    f32x16 accs[2];
#pragma unroll
    for (int i = 0; i < 16; ++i) { accs[0][i] = 0.f; accs[1][i] = 0.f; }

    int tp = 2 * p + 2;               // tile p trips (<= 32, all in phase A)
    for (int ks = 0; ks < 32; ++ks) {
        short8 bfrag = *(const short8*)(bbase + ks * 512);
        short8 a1 = *(const short8*)&Krow[xq + 16 * ks];
        accs[1] = __builtin_amdgcn_mfma_f32_32x32x16_bf16(a1, bfrag, accs[1], 0, 0, 0);
        if (ks < tp) {
            short8 a2 = *(const short8*)&Krow[xp + 16 * ks];
            accs[0] = __builtin_amdgcn_mfma_f32_32x32x16_bf16(a2, bfrag, accs[0], 0, 0, 0);
        }
    }
    __syncthreads();
    // ---- stage Us window B: j in [512,1024) ----
    {
        uint4* dstl = (uint4*)Us;
        for (int v = t; v < 2048; v += 256) dstl[v] = usrc[v + 2048];
    }
    __syncthreads();
    int tq = 2 * q - 30;              // remaining trips for tile q
    for (int ks2 = 0; ks2 < tq; ++ks2) {
        short8 bfrag = *(const short8*)(bbase + ks2 * 512);
        short8 a1 = *(const short8*)&Krow[xq + 16 * (32 + ks2)];
        accs[1] = __builtin_amdgcn_mfma_f32_32x32x16_bf16(a1, bfrag, accs[1], 0, 0, 0);
    }

    // ---- epilogue: skip + GELU + pg2[b][d][l], 8B vector stores ----
    // C col = mm = batch, row = (reg&3) + 8*(reg>>2) + 4*h = rr + 8*rg + 4*h
    float Dd = Dp[d];
#pragma unroll
    for (int c2 = 0; c2 < 2; ++c2) {
        int I = c2 ? q : p;
        size_t rowb = ((size_t)(mm * D_MODEL + d) << 10) + 32 * I;
#pragma unroll
        for (int rg = 0; rg < 4; ++rg) {
            const short* sp = u_bfT + ((size_t)d << 15) + (4 * I + rg) * 256 + mm * 8 + 4 * h;
            short4v us = *(const short4v*)sp;
            short4v pk;
#pragma unroll
            for (int rr = 0; rr < 4; ++rr) {
                float v = gelu_cheb(accs[c2][rg * 4 + rr] + bf2f(us[rr]) * Dd);
                pk[rr] = (short)f2bf(v);
            }
            *(short4v*)(pg2 + rowb + 8 * rg + 4 * h) = pk;
        }
    }
}

// ---------------- Kernel 3: MFMA GEMM + GLU gate + pooling, LDS-staged B ----------------
// x staged from pg2[b][d][l] into xs[l][k] bf16 (stride 136); B-frags from LDS.
__global__ __launch_bounds__(256) void k_glu2(const short* __restrict__ pg2,
                                              const short* __restrict__ w1bf,
                                              const float* __restrict__ b1,
                                              const float* __restrict__ Wdec,
                                              float* __restrict__ acc2) {
    __shared__ __align__(16) short xs[64 * 136];   // 17.4 KB
    __shared__ float red[4];
    int b = blockIdx.y;
    int lc = blockIdx.x;
    int l0 = lc * 64;
    int t = threadIdx.x;

    // ---- stage: thread = (d-pair dp, l-quarter lq); ds_write_b32 pairs ----
    {
        int dp = t & 63, lq = t >> 6;
        const short* r0 = pg2 + (((size_t)b * D_MODEL + 2 * dp) << 10) + l0 + lq * 16;
        short8 a0 = *(const short8*)r0;            // k=2dp,   l = lq*16+0..7
        short8 a1 = *(const short8*)(r0 + 8);      //          l = lq*16+8..15
        short8 c0 = *(const short8*)(r0 + 1024);   // k=2dp+1
        short8 c1 = *(const short8*)(r0 + 1032);
#pragma unroll
        for (int i = 0; i < 8; ++i) {
            *(unsigned*)&xs[(lq * 16 + i) * 136 + 2 * dp] =
                (unsigned)(unsigned short)a0[i] | ((unsigned)(unsigned short)c0[i] << 16);
            *(unsigned*)&xs[(lq * 16 + 8 + i) * 136 + 2 * dp] =
                (unsigned)(unsigned short)a1[i] | ((unsigned)(unsigned short)c1[i] << 16);
        }
    }

    int wv = t >> 6, lane = t & 63;
    int m = lane & 15, q = lane >> 4;

    const short* wA0 = w1bf + ((2 * wv + 0) * 16 + m) * D_MODEL;
    const short* wA1 = w1bf + ((2 * wv + 1) * 16 + m) * D_MODEL;

    short8 aA0[4], aA1[4], aB0[4], aB1[4];
#pragma unroll
    for (int kki = 0; kki < 4; ++kki) {
        int ko = kki * 32 + q * 8;
        aA0[kki] = *(const short8*)(wA0 + ko);
        aA1[kki] = *(const short8*)(wA1 + ko);
        aB0[kki] = *(const short8*)(wA0 + 128 * D_MODEL + ko);
        aB1[kki] = *(const short8*)(wA1 + 128 * D_MODEL + ko);
    }
    __syncthreads();

    f32x4 accA[2][4], accB[2][4];
#pragma unroll
    for (int p = 0; p < 2; ++p)
#pragma unroll
        for (int nt = 0; nt < 4; ++nt) {
            accA[p][nt] = (f32x4){0.f, 0.f, 0.f, 0.f};
            accB[p][nt] = (f32x4){0.f, 0.f, 0.f, 0.f};
        }

#pragma unroll
    for (int kki = 0; kki < 4; ++kki) {
        int ko = kki * 32 + q * 8;
        short8 bfr[4];
#pragma unroll
        for (int nt = 0; nt < 4; ++nt)
            bfr[nt] = *(const short8*)&xs[(nt * 16 + m) * 136 + ko];
#pragma unroll
        for (int nt = 0; nt < 4; ++nt) {
            accA[0][nt] = __builtin_amdgcn_mfma_f32_16x16x32_bf16(aA0[kki], bfr[nt], accA[0][nt], 0, 0, 0);
            accA[1][nt] = __builtin_amdgcn_mfma_f32_16x16x32_bf16(aA1[kki], bfr[nt], accA[1][nt], 0, 0, 0);
            accB[0][nt] = __builtin_amdgcn_mfma_f32_16x16x32_bf16(aB0[kki], bfr[nt], accB[0][nt], 0, 0, 0);
            accB[1][nt] = __builtin_amdgcn_mfma_f32_16x16x32_bf16(aB1[kki], bfr[nt], accB[1][nt], 0, 0, 0);
        }
    }

    float s = 0.f;
#pragma unroll
    for (int p = 0; p < 2; ++p) {
        int oA = (2 * wv + p) * 16 + q * 4;
#pragma unroll
        for (int r = 0; r < 4; ++r) {
            int o = oA + r;
            float wd  = Wdec[o];
            float ba  = b1[o];
            float bb1 = b1[o + 128];
#pragma unroll
            for (int nt = 0; nt < 4; ++nt) {
                float aa  = accA[p][nt][r] + ba;
                float bbv = accB[p][nt][r] + bb1;
                float g = fminf(fmaxf(0.25f * bbv + 0.5f, 0.f), 1.f);
                s += wd * aa * g;
            }
        }
    }
#pragma unroll
    for (int off = 32; off > 0; off >>= 1) s += __shfl_down(s, off, 64);
    if (lane == 0) red[wv] = s;
    __syncthreads();
    if (t == 0) acc2[b * 16 + lc] = red[0] + red[1] + red[2] + red[3];
}

// ---------------- Kernel 4: finalize ----------------
__global__ void k_finish(const float* __restrict__ acc2, const float* __restrict__ bdec,
                         float* __restrict__ out) {
    int b = threadIdx.x;
    if (b < BATCH) {
        float s = 0.f;
#pragma unroll
        for (int c = 0; c < 16; ++c) s += acc2[b * 16 + c];
        out[b] = s * (1.0f / (float)LEN) + bdec[0];
    }
}

extern "C" void kernel_launch(void* const* d_in, const int* in_sizes, int n_in,
                              void* d_out, int out_size, void* d_ws, size_t ws_size,
                              hipStream_t stream) {
    const float* u          = (const float*)d_in[0];
    const float* log_dt     = (const float*)d_in[1];
    const float* log_A_real = (const float*)d_in[2];
    const float* A_imag     = (const float*)d_in[3];
    const float* B_re       = (const float*)d_in[4];
    const float* B_im       = (const float*)d_in[5];
    const float* C_re       = (const float*)d_in[6];
    const float* C_im       = (const float*)d_in[7];
    const float* Dp         = (const float*)d_in[8];
    const float* W1         = (const float*)d_in[9];
    const float* b1         = (const float*)d_in[10];
    const float* Wdec       = (const float*)d_in[11];
    const float* bdec       = (const float*)d_in[12];
    float* out = (float*)d_out;

    float* w = (float*)d_ws;
    float* K      = w;                                    // 128*1064 f32 (padded)
    float* acc2   = K + (size_t)D_MODEL * KROW;           // 512 floats
    short* u_bfT  = (short*)(acc2 + 512);                 // [d][j>>3][b][j&7] bf16
    short* pg2    = u_bfT + (size_t)BATCH * D_MODEL * LEN; // [b][d][l] bf16
    short* w1bf   = pg2 + (size_t)BATCH * LEN * D_MODEL;  // 256*128 bf16

    k_genK4<<<D_MODEL * 8, 256, 0, stream>>>(log_dt, log_A_real, A_imag, B_re, B_im,
                                             C_re, C_im, W1, u, w1bf, u_bfT, K);
    k_conv9<<<512, 256, 0, stream>>>(K, u_bfT, Dp, pg2);
    k_glu2<<<dim3(16, BATCH), 256, 0, stream>>>(pg2, w1bf, b1, Wdec, acc2);
    k_finish<<<1, 64, 0, stream>>>(acc2, bdec, out);
}